// Round 4
// baseline (262.289 us; speedup 1.0000x reference)
//
#include <hip/hip_runtime.h>

#define NEG_SLOPE 0.2f
#define D 64
#define TILE 256   // output tile is TILE x TILE; block has TILE threads

// Fused: each block computes the 256 s1-dots and 256 s2-dots for its tile
// directly from Wh (2 MB, L2/L3-resident), then writes the 256x256
// leaky_relu(s1[i]+s2[j]) tile. Removes the separate gemv launch, the
// s round-trip through memory, and the inter-kernel dependency.
__global__ __launch_bounds__(256) void fused_kernel(const float* __restrict__ Wh,
                                                    const float* __restrict__ a,
                                                    float* __restrict__ out,
                                                    int N) {
    __shared__ float a_lds[2 * D];
    __shared__ float s1_lds[TILE];
    __shared__ float s2_lds[TILE];

    const int t  = threadIdx.x;
    const int r0 = blockIdx.y * TILE;
    const int c0 = blockIdx.x * TILE;

    if (t < 2 * D) a_lds[t] = a[t];
    __syncthreads();

    // Phase 1: thread t computes s1 for row (r0+t) and s2 for row (c0+t).
    // Wh rows are 256 B; float4 loads, a from LDS (broadcast reads).
    {
        const float4* __restrict__ wr = reinterpret_cast<const float4*>(Wh + (size_t)(r0 + t) * D);
        const float4* __restrict__ wc = reinterpret_cast<const float4*>(Wh + (size_t)(c0 + t) * D);
        const float4* __restrict__ a1 = reinterpret_cast<const float4*>(a_lds);
        const float4* __restrict__ a2 = reinterpret_cast<const float4*>(a_lds + D);
        float sum1 = 0.f, sum2 = 0.f;
        #pragma unroll
        for (int k = 0; k < D / 4; ++k) {
            const float4 w1 = wr[k], v1 = a1[k];
            sum1 += w1.x * v1.x + w1.y * v1.y + w1.z * v1.z + w1.w * v1.w;
            const float4 w2 = wc[k], v2 = a2[k];
            sum2 += w2.x * v2.x + w2.y * v2.y + w2.z * v2.z + w2.w * v2.w;
        }
        s1_lds[t] = sum1;
        s2_lds[t] = sum2;
    }
    __syncthreads();

    // Phase 2: write the tile. Wave w owns rows [r0+w*64, r0+w*64+64);
    // its 64 lanes cover the 256-float column segment as float4 each ->
    // one contiguous 1 KB store per wave per iteration.
    const int w = t >> 6;           // wave in block, 0..3
    const int l = t & 63;           // lane
    const float4 s2 = reinterpret_cast<const float4*>(s2_lds)[l];  // conflict-free b128 reads
    const int n4 = N >> 2;

    #pragma unroll 4
    for (int i = 0; i < 64; ++i) {
        const int row = r0 + (w << 6) + i;
        const float s1 = s1_lds[(w << 6) + i];   // wave-uniform LDS broadcast
        float4 e;
        e.x = s1 + s2.x;
        e.y = s1 + s2.y;
        e.z = s1 + s2.z;
        e.w = s1 + s2.w;
        e.x = (e.x >= 0.f) ? e.x : NEG_SLOPE * e.x;
        e.y = (e.y >= 0.f) ? e.y : NEG_SLOPE * e.y;
        e.z = (e.z >= 0.f) ? e.z : NEG_SLOPE * e.z;
        e.w = (e.w >= 0.f) ? e.w : NEG_SLOPE * e.w;
        reinterpret_cast<float4*>(out)[(size_t)row * n4 + (c0 >> 2) + l] = e;
    }
}

extern "C" void kernel_launch(void* const* d_in, const int* in_sizes, int n_in,
                              void* d_out, int out_size, void* d_ws, size_t ws_size,
                              hipStream_t stream) {
    const float* Wh = (const float*)d_in[0];   // (N, 64) fp32
    const float* a  = (const float*)d_in[1];   // (128, 1) fp32
    float* out = (float*)d_out;                // (N, N) fp32

    const int N = in_sizes[0] / D;             // 8192 (in_sizes in elements)

    dim3 grid(N / TILE, N / TILE);             // (32, 32)
    fused_kernel<<<grid, TILE, 0, stream>>>(Wh, a, out, N);
}

// Round 5
// 251.574 us; speedup vs baseline: 1.0426x; 1.0426x over previous
//
#include <hip/hip_runtime.h>

#define NEG_SLOPE 0.2f
#define D 64

// Kernel 1: s1[i] = Wh[i,:] . a[:64],  s2[i] = Wh[i,:] . a[64:]
// One 64-lane wave per row. Lane k handles element k (coalesced loads).
__global__ __launch_bounds__(256) void gemv2_kernel(const float* __restrict__ Wh,
                                                    const float* __restrict__ a,
                                                    float* __restrict__ s,  // s[0..N)=s1, s[N..2N)=s2
                                                    int N) {
    const int gtid = blockIdx.x * blockDim.x + threadIdx.x;
    const int row  = gtid >> 6;          // wave index
    const int lane = threadIdx.x & 63;
    if (row >= N) return;

    const float w  = Wh[row * D + lane];
    float sum1 = w * a[lane];
    float sum2 = w * a[D + lane];

    #pragma unroll
    for (int off = 32; off > 0; off >>= 1) {
        sum1 += __shfl_down(sum1, off, 64);
        sum2 += __shfl_down(sum2, off, 64);
    }
    if (lane == 0) {
        s[row]     = sum1;
        s[N + row] = sum2;
    }
}

// Kernel 2: out[i][j] = leaky_relu(s1[i] + s2[j]). One float4 per thread.
// Proven-fastest structure (251.6 us): temporal stores, grid (N/4/256, N).
// Each block writes 4 KB fully contiguous; consecutive blocks sweep a row
// before advancing -> best DRAM write-page locality. (Fused-tile variant
// with 1 KB strided bursts measured +10 us: write contiguity dominates.)
__global__ __launch_bounds__(256) void expand_kernel(const float* __restrict__ s,
                                                     float* __restrict__ out,
                                                     int N) {
    const int row = blockIdx.y;
    const int c4  = blockIdx.x * blockDim.x + threadIdx.x;   // float4 column index
    const float s1 = s[row];
    const float4 s2 = reinterpret_cast<const float4*>(s + N)[c4];

    float4 e;
    e.x = s1 + s2.x;
    e.y = s1 + s2.y;
    e.z = s1 + s2.z;
    e.w = s1 + s2.w;
    e.x = (e.x >= 0.f) ? e.x : NEG_SLOPE * e.x;
    e.y = (e.y >= 0.f) ? e.y : NEG_SLOPE * e.y;
    e.z = (e.z >= 0.f) ? e.z : NEG_SLOPE * e.z;
    e.w = (e.w >= 0.f) ? e.w : NEG_SLOPE * e.w;

    reinterpret_cast<float4*>(out)[(size_t)row * (N >> 2) + c4] = e;
}

extern "C" void kernel_launch(void* const* d_in, const int* in_sizes, int n_in,
                              void* d_out, int out_size, void* d_ws, size_t ws_size,
                              hipStream_t stream) {
    const float* Wh = (const float*)d_in[0];   // (N, 64) fp32
    const float* a  = (const float*)d_in[1];   // (128, 1) fp32
    float* out = (float*)d_out;                // (N, N) fp32
    float* s   = (float*)d_ws;                 // 2N floats of scratch

    const int N = in_sizes[0] / D;             // 8192

    // Kernel 1: N waves -> N*64 threads, 256-thread blocks (4 waves/block)
    {
        const int threads = 256;
        const int blocks  = (N * 64 + threads - 1) / threads;
        gemv2_kernel<<<blocks, threads, 0, stream>>>(Wh, a, s, N);
    }

    // Kernel 2: grid (N/4/256, N), each thread writes one float4
    {
        const int threads = 256;
        dim3 grid((N / 4) / threads, N);
        expand_kernel<<<grid, threads, 0, stream>>>(s, out, N);
    }
}